// Round 3
// baseline (836.399 us; speedup 1.0000x reference)
//
#include <hip/hip_runtime.h>
#include <hip/hip_bf16.h>
#include <stdint.h>

#define TOKENS 2048
#define DMODEL 1024
#define HID    2048
#define NEXP   8
#define VOCAB  32000
#define ROWCAP 5120      // 4096 rows + 8*127 pad, rounded to 40*128
#define MAXTILES 40
#define LN_EPS 1e-5f

typedef __hip_bfloat16 bf16;
typedef __bf16 v8bf __attribute__((ext_vector_type(8)));
typedef float  v4f  __attribute__((ext_vector_type(4)));

// control block (ints) at ws offset 0
#define CTL_COUNTS 0    // 8
#define CTL_CURSOR 8    // 8
#define CTL_PADOFF 16   // 9
#define CTL_TILE2E 32   // 40
#define CTL_NTILES 72
#define CTL_INTS   80

typedef __attribute__((address_space(3))) uint32_t lds_u32_t;
typedef __attribute__((address_space(1))) uint32_t glb_u32_t;

__device__ __forceinline__ void gl2lds16(const void* g, void* l) {
  // async global->LDS, 16B per lane; LDS dst is wave-uniform base + lane*16
  __builtin_amdgcn_global_load_lds((glb_u32_t*)(uintptr_t)g,
                                   (lds_u32_t*)(uintptr_t)l, 16, 0, 0);
}

// ---------------- embed gather + gate softmax + top2 ----------------
__global__ __launch_bounds__(256) void embed_gate(
    const int* __restrict__ x, const float* __restrict__ embed,
    const float* __restrict__ Wg, const float* __restrict__ bg,
    bf16* __restrict__ h_bf, int* __restrict__ top2i, float* __restrict__ top2w,
    int* __restrict__ ctl)
{
  const int t = blockIdx.x, tid = threadIdx.x;
  const int xid = x[t];
  const float4 hv = ((const float4*)(embed + (size_t)xid * DMODEL))[tid];

  union { ushort4 u; bf16 b[4]; } pk;
  pk.b[0] = __float2bfloat16(hv.x); pk.b[1] = __float2bfloat16(hv.y);
  pk.b[2] = __float2bfloat16(hv.z); pk.b[3] = __float2bfloat16(hv.w);
  ((ushort4*)(h_bf + (size_t)t * DMODEL))[tid] = pk.u;

  float acc[8] = {0,0,0,0,0,0,0,0};
  const float hk[4] = {hv.x, hv.y, hv.z, hv.w};
  #pragma unroll
  for (int u = 0; u < 4; ++u) {
    const float* wr = Wg + (size_t)(tid*4 + u) * NEXP;
    #pragma unroll
    for (int e = 0; e < 8; ++e) acc[e] += hk[u] * wr[e];
  }
  #pragma unroll
  for (int e = 0; e < 8; ++e)
    for (int off = 32; off >= 1; off >>= 1)
      acc[e] += __shfl_down(acc[e], off, 64);

  __shared__ float sred[4][8];
  const int lane = tid & 63, wave = tid >> 6;
  if (lane == 0) {
    #pragma unroll
    for (int e = 0; e < 8; ++e) sred[wave][e] = acc[e];
  }
  __syncthreads();
  if (tid == 0) {
    float lg[8];
    #pragma unroll
    for (int e = 0; e < 8; ++e)
      lg[e] = sred[0][e] + sred[1][e] + sred[2][e] + sred[3][e] + bg[e];
    float m = lg[0];
    #pragma unroll
    for (int e = 1; e < 8; ++e) m = fmaxf(m, lg[e]);
    float p[8], s = 0.f;
    #pragma unroll
    for (int e = 0; e < 8; ++e) { p[e] = expf(lg[e] - m); s += p[e]; }
    const float inv = 1.f / s;
    int i0 = 0;
    for (int e = 1; e < 8; ++e) if (p[e] > p[i0]) i0 = e;
    int i1 = -1;
    for (int e = 0; e < 8; ++e) { if (e == i0) continue; if (i1 < 0 || p[e] > p[i1]) i1 = e; }
    top2i[2*t] = i0; top2i[2*t+1] = i1;
    top2w[2*t] = p[i0]*inv; top2w[2*t+1] = p[i1]*inv;
    atomicAdd(&ctl[CTL_COUNTS + i0], 1);
    atomicAdd(&ctl[CTL_COUNTS + i1], 1);
  }
}

// ---------------- bucket tokens per expert (128-aligned segments) ----------------
__global__ __launch_bounds__(256) void scatter_k(
    const int* __restrict__ top2i, int* __restrict__ ctl,
    int* __restrict__ tok2row, int* __restrict__ rowtok)
{
  __shared__ int spad[8];
  const int tid = threadIdx.x;
  for (int r = tid; r < ROWCAP; r += 256) rowtok[r] = 0;   // pad rows -> token 0 (harmless)
  if (tid == 0) {
    int off = 0, gm = 0;
    for (int e = 0; e < 8; ++e) {
      spad[e] = off; ctl[CTL_PADOFF + e] = off;
      int nt = (ctl[CTL_COUNTS + e] + 127) >> 7;
      for (int i = 0; i < nt; ++i) ctl[CTL_TILE2E + gm++] = e;
      off += nt << 7;
    }
    ctl[CTL_PADOFF + 8] = off;
    ctl[CTL_NTILES] = gm;
  }
  __syncthreads();
  for (int idx = tid; idx < 2*TOKENS; idx += 256) {
    const int e = top2i[idx];
    const int pos = spad[e] + atomicAdd(&ctl[CTL_CURSOR + e], 1);
    tok2row[idx] = pos;
    rowtok[pos] = idx >> 1;
  }
}

// ---------------- fp32 [b][R][C] -> bf16 [b][C][R] (B^T layout for MFMA) ----------------
__global__ __launch_bounds__(256) void transpose_cvt(
    const float* __restrict__ in, bf16* __restrict__ out, int R, int C)
{
  __shared__ float tile[32][33];
  const int b = blockIdx.z;
  in  += (size_t)b * R * C;
  out += (size_t)b * R * C;
  const int ct = blockIdx.x * 32, rt = blockIdx.y * 32;
  const int lc = threadIdx.x & 31, lr = threadIdx.x >> 5;  // 0..31, 0..7
  #pragma unroll
  for (int i = 0; i < 4; ++i) {
    const int r = lr + i*8;
    tile[r][lc] = in[(size_t)(rt + r) * C + ct + lc];
  }
  __syncthreads();
  #pragma unroll
  for (int i = 0; i < 4; ++i) {
    const int r = lr + i*8;
    out[(size_t)(ct + r) * R + rt + lc] = __float2bfloat16(tile[lc][r]);
  }
}

// ---------------- 128x128x32 bf16 MFMA GEMM (m97 structure + rotation swizzle) ----------------
// LDS [row][32] with physical slot s holding logical granule s ^ ((row>>?)…):
//   writer (linear gl2lds) thread maps (row = l>>2, slot = l&3) -> source granule
//   (l&3)^((l>>2)&3); reader uses slot lq^(lr&3). Read bank-quad
//   (row*4 + slot)&7 is uniform over the wave -> conflict-free (was 8-way).
// MODE 0: a_act = relu(h[rowtok] @ W1t[e]^T + b1[e])  K=1024 N=2048, bf16 out
// MODE 1: y     =       a_act @ W2t[e]^T + b2[e]      K=2048 N=1024, f32 out
template<int MODE>
__global__ __launch_bounds__(256) void gemm128(
    const bf16* __restrict__ Abase, const bf16* __restrict__ Btbase,
    const float* __restrict__ bias, float* __restrict__ outF, bf16* __restrict__ outB,
    const int* __restrict__ ctl, const int* __restrict__ rowtok)
{
  constexpr int K = (MODE == 1) ? HID : DMODEL;
  constexpr int N = (MODE == 0) ? HID : DMODEL;
  const int gm = blockIdx.x, gn = blockIdx.y;

  int eid = 0;
  if (gm >= ctl[CTL_NTILES]) return;
  eid = ctl[CTL_TILE2E + gm];

  __shared__ bf16 As[128 * 32];
  __shared__ bf16 Bs[128 * 32];
  __shared__ int  rts[128];

  const int tid = threadIdx.x, lane = tid & 63, wave = tid >> 6;
  const bf16* Bt = Btbase + (size_t)eid * (size_t)N * K + (size_t)(gn * 128) * K;
  const float* bv = bias + (size_t)eid * N + gn * 128;

  if constexpr (MODE == 0) {
    if (tid < 128) rts[tid] = rowtok[gm * 128 + tid];
    __syncthreads();
  }

  // staging coords: chunk c = 16 rows; wave handles chunks {wave, wave+4}
  const int srow = lane >> 2;          // row within chunk
  const int scol = 8 * ((lane & 3) ^ ((lane >> 2) & 3));   // rotation-swizzled source col
  const int r0 = wave * 16 + srow, r1 = (wave + 4) * 16 + srow;
  size_t ga0, ga1;
  if constexpr (MODE == 0) { ga0 = (size_t)rts[r0]; ga1 = (size_t)rts[r1]; }
  else { ga0 = (size_t)(gm * 128 + r0); ga1 = (size_t)(gm * 128 + r1); }
  const bf16* aptr0 = Abase + ga0 * K + scol;
  const bf16* aptr1 = Abase + ga1 * K + scol;
  const bf16* bptr0 = Bt + (size_t)r0 * K + scol;
  const bf16* bptr1 = Bt + (size_t)r1 * K + scol;

  const int wm = (wave & 1) * 64, wn = (wave >> 1) * 64;
  const int lr = lane & 15, lq = lane >> 4;
  const int rot = (lq ^ (lr & 3)) * 8;   // swizzled read slot (bf16 elems)

  v4f acc[4][4] = {};

  for (int k0 = 0; k0 < K; k0 += 32) {
    gl2lds16(aptr0 + k0, &As[wave * 512]);
    gl2lds16(aptr1 + k0, &As[(wave + 4) * 512]);
    gl2lds16(bptr0 + k0, &Bs[wave * 512]);
    gl2lds16(bptr1 + k0, &Bs[(wave + 4) * 512]);
    __syncthreads();

    v8bf af[4], bfg[4];
    #pragma unroll
    for (int i = 0; i < 4; ++i) af[i]  = *(const v8bf*)&As[(wm + i*16 + lr) * 32 + rot];
    #pragma unroll
    for (int j = 0; j < 4; ++j) bfg[j] = *(const v8bf*)&Bs[(wn + j*16 + lr) * 32 + rot];
    #pragma unroll
    for (int i = 0; i < 4; ++i)
      #pragma unroll
      for (int j = 0; j < 4; ++j)
        acc[i][j] = __builtin_amdgcn_mfma_f32_16x16x32_bf16(af[i], bfg[j], acc[i][j], 0, 0, 0);
    __syncthreads();
  }

  float bb[4];
  #pragma unroll
  for (int j = 0; j < 4; ++j) bb[j] = bv[wn + j*16 + lr];

  #pragma unroll
  for (int i = 0; i < 4; ++i) {
    #pragma unroll
    for (int j = 0; j < 4; ++j) {
      #pragma unroll
      for (int r = 0; r < 4; ++r) {
        const int row = gm * 128 + wm + i*16 + lq*4 + r;
        const int col = gn * 128 + wn + j*16 + lr;
        float v = acc[i][j][r] + bb[j];
        if constexpr (MODE == 0) {
          v = v > 0.f ? v : 0.f;
          outB[(size_t)row * N + col] = __float2bfloat16(v);
        } else {
          outF[(size_t)row * (size_t)N + col] = v;
        }
      }
    }
  }
}

// ================= head GEMM: 256x128xBK32, 2 blocks/CU (TLP overlap) =================
// out[2048][32000] = lnb[2048][1024] @ Wht[32000][1024]^T + bh
// 8 waves as 4M x 2N, per-wave 64x64 output (acc 64 regs, frags 32 -> <=128 VGPR,
// __launch_bounds__(512,4) => 2 blocks/CU). LDS 48KB: dbuf x (A 16KB + B 8KB).
// Rationale (round-3): with one 128KB block/CU the barrier phases serialize LDS
// reads / staging / MFMA (MfmaUtil capped ~32%). Two co-resident blocks run out
// of phase and keep the CU matrix pipe fed (m114 implicit wave-level overlap).
// XCD locality: M=2048 -> exactly 8 m-tiles; block orig -> XCD orig&7 computes
// m-tile orig&7, so each XCD pins one 512KB A-panel in L2 and streams B once,
// with all XCDs in lockstep on n (L3 temporal locality for B).
// Rotation swizzle (round-2, measured conflict-free): slot = lq ^ (lr&3), source
// granule pre-swizzled so gl2lds dest stays linear (rule #21).
__global__ __launch_bounds__(512, 4) void gemm_head(
    const bf16* __restrict__ A, const bf16* __restrict__ Bt,
    const float* __restrict__ bias, float* __restrict__ out)
{
  constexpr int K = DMODEL;    // 1024
  constexpr int N = VOCAB;     // 32000
  __shared__ char smem[49152]; // A: [2][16KB] @ 0, B: [2][8KB] @ 32768

  const int orig = blockIdx.x;
  const int tm0 = (orig & 7) * 256;   // m-tile == XCD id (dispatch round-robin, m09)
  const int tn0 = (orig >> 3) * 128;

  const int tid = threadIdx.x;
  const int lane = tid & 63, wv = tid >> 6;
  const int lr = lane & 15, lq = lane >> 4;
  const int wr = wv & 3, wc = wv >> 2;          // 4M x 2N wave grid

  // staging: thread t -> physical (row t>>2, slot t&3); source granule pre-swizzled
  const int r_s = tid >> 2;
  const int c_s = 8 * ((tid & 3) ^ ((tid >> 2) & 3));
  const bf16* aP0 = A  + (size_t)(tm0 + r_s) * K + c_s;        // A rows 0-127
  const bf16* aP1 = A  + (size_t)(tm0 + 128 + r_s) * K + c_s;  // A rows 128-255
  const bf16* bP  = Bt + (size_t)(tn0 + r_s) * K + c_s;        // B rows 0-127
  char* const dA0 = smem + wv * 1024;           // + buf*16384
  char* const dA1 = smem + 8192 + wv * 1024;    // + buf*16384
  char* const dB  = smem + 32768 + wv * 1024;   // + buf*8192

  // fragment-read byte bases (conflict-free: quad = (row*4 + slot)&7 uniform)
  const int rot = (lq ^ (lr & 3)) * 16;
  const int aRd = (wr * 64 + lr) * 64 + rot;            // + i*1024 + buf*16384
  const int bRd = 32768 + (wc * 64 + lr) * 64 + rot;    // + j*1024 + buf*8192

  v4f acc[4][4] = {};

  // prologue: stage tile 0 into buf0
  gl2lds16(aP0, dA0);
  gl2lds16(aP1, dA1);
  gl2lds16(bP,  dB);
  asm volatile("s_waitcnt vmcnt(0)" ::: "memory");
  __builtin_amdgcn_s_barrier();
  __builtin_amdgcn_sched_barrier(0);

  for (int kt = 0; kt < 32; ++kt) {
    const int cur = kt & 1;
    if (kt < 31) {                       // stage tile kt+1 into other buffer FIRST
      const int k0n = (kt + 1) * 32;
      const int nb = cur ^ 1;
      gl2lds16(aP0 + k0n, dA0 + nb * 16384);
      gl2lds16(aP1 + k0n, dA1 + nb * 16384);
      gl2lds16(bP  + k0n, dB  + nb * 8192);
    }
    const char* sa = smem + cur * 16384 + aRd;
    const char* sb = smem + cur * 8192  + bRd;
    v8bf a[4], b[4];
    #pragma unroll
    for (int i = 0; i < 4; ++i) a[i] = *(const v8bf*)(sa + i * 1024);
    #pragma unroll
    for (int j = 0; j < 4; ++j) b[j] = *(const v8bf*)(sb + j * 1024);
    __builtin_amdgcn_s_setprio(1);
    #pragma unroll
    for (int i = 0; i < 4; ++i)
      #pragma unroll
      for (int j = 0; j < 4; ++j)
        acc[i][j] = __builtin_amdgcn_mfma_f32_16x16x32_bf16(a[i], b[j], acc[i][j], 0, 0, 0);
    __builtin_amdgcn_s_setprio(0);
    __builtin_amdgcn_sched_barrier(0);
    asm volatile("s_waitcnt vmcnt(0)" ::: "memory");   // this iter's 3 loads arrived
    __builtin_amdgcn_s_barrier();
    __builtin_amdgcn_sched_barrier(0);
  }

  // epilogue: bias + fp32 store
  const int col0 = tn0 + wc * 64 + lr;
  const size_t row0 = (size_t)(tm0 + wr * 64 + lq * 4);
  float bb[4];
  #pragma unroll
  for (int j = 0; j < 4; ++j) bb[j] = bias[col0 + j * 16];
  #pragma unroll
  for (int i = 0; i < 4; ++i)
    #pragma unroll
    for (int j = 0; j < 4; ++j)
      #pragma unroll
      for (int r = 0; r < 4; ++r)
        out[(row0 + i * 16 + r) * (size_t)N + col0 + j * 16] = acc[i][j][r] + bb[j];
}

// ---------------- combine top2 expert outputs + LayerNorm -> bf16 ----------------
__global__ __launch_bounds__(256) void combine_ln(
    const float* __restrict__ y, const int* __restrict__ tok2row,
    const float* __restrict__ top2w, const float* __restrict__ gamma,
    const float* __restrict__ beta, bf16* __restrict__ ln)
{
  const int t = blockIdx.x, tid = threadIdx.x;
  const int rr0 = tok2row[2*t], rr1 = tok2row[2*t+1];
  const float w0 = top2w[2*t], w1 = top2w[2*t+1];
  const float4 a = ((const float4*)(y + (size_t)rr0 * DMODEL))[tid];
  const float4 b = ((const float4*)(y + (size_t)rr1 * DMODEL))[tid];
  const float c0 = w0*a.x + w1*b.x, c1 = w0*a.y + w1*b.y;
  const float c2 = w0*a.z + w1*b.z, c3 = w0*a.w + w1*b.w;

  float s1 = c0 + c1 + c2 + c3;
  float s2 = c0*c0 + c1*c1 + c2*c2 + c3*c3;
  for (int off = 32; off >= 1; off >>= 1) {
    s1 += __shfl_down(s1, off, 64);
    s2 += __shfl_down(s2, off, 64);
  }
  __shared__ float rs1[4], rs2[4];
  __shared__ float smu, srs;
  const int lane = tid & 63, wave = tid >> 6;
  if (lane == 0) { rs1[wave] = s1; rs2[wave] = s2; }
  __syncthreads();
  if (tid == 0) {
    const float S1 = rs1[0] + rs1[1] + rs1[2] + rs1[3];
    const float S2 = rs2[0] + rs2[1] + rs2[2] + rs2[3];
    const float mu = S1 / DMODEL;
    const float var = S2 / DMODEL - mu * mu;
    smu = mu; srs = rsqrtf(var + LN_EPS);
  }
  __syncthreads();
  const float mu = smu, rstd = srs;
  const float4 g  = ((const float4*)gamma)[tid];
  const float4 be = ((const float4*)beta)[tid];
  union { ushort4 u; bf16 bb[4]; } pk;
  pk.bb[0] = __float2bfloat16((c0 - mu) * rstd * g.x + be.x);
  pk.bb[1] = __float2bfloat16((c1 - mu) * rstd * g.y + be.y);
  pk.bb[2] = __float2bfloat16((c2 - mu) * rstd * g.z + be.z);
  pk.bb[3] = __float2bfloat16((c3 - mu) * rstd * g.w + be.w);
  ((ushort4*)(ln + (size_t)t * DMODEL))[tid] = pk.u;
}

// ---------------- host ----------------
extern "C" void kernel_launch(void* const* d_in, const int* in_sizes, int n_in,
                              void* d_out, int out_size, void* d_ws, size_t ws_size,
                              hipStream_t stream)
{
  (void)in_sizes; (void)n_in; (void)out_size; (void)ws_size;
  const int*   x     = (const int*)d_in[0];
  const float* embed = (const float*)d_in[1];
  const float* Wg    = (const float*)d_in[2];
  const float* bg    = (const float*)d_in[3];
  const float* W1    = (const float*)d_in[4];
  const float* b1    = (const float*)d_in[5];
  const float* W2    = (const float*)d_in[6];
  const float* b2    = (const float*)d_in[7];
  const float* gamma = (const float*)d_in[8];
  const float* beta  = (const float*)d_in[9];
  const float* Wh    = (const float*)d_in[10];
  const float* bh    = (const float*)d_in[11];
  float* out = (float*)d_out;

  char* ws = (char*)d_ws;
  size_t o = 0;
  int* ctl = (int*)(ws + o);        o += 1024;
  bf16* h_bf = (bf16*)(ws + o);     o += (size_t)TOKENS * DMODEL * 2;
  int* top2i = (int*)(ws + o);      o += (size_t)TOKENS * 2 * 4;
  float* top2w = (float*)(ws + o);  o += (size_t)TOKENS * 2 * 4;
  int* tok2row = (int*)(ws + o);    o += (size_t)TOKENS * 2 * 4;
  int* rowtok = (int*)(ws + o);     o += (size_t)ROWCAP * 4;
  o = (o + 255) & ~(size_t)255;
  bf16* a_act = (bf16*)(ws + o);    o += (size_t)ROWCAP * HID * 2;
  float* yrow = (float*)(ws + o);   o += (size_t)ROWCAP * DMODEL * 4;
  bf16* lnb = (bf16*)(ws + o);      o += (size_t)TOKENS * DMODEL * 2;
  bf16* W1t = (bf16*)(ws + o);      o += (size_t)NEXP * DMODEL * HID * 2;
  bf16* W2t = (bf16*)(ws + o);      o += (size_t)NEXP * DMODEL * HID * 2;
  bf16* Wht = (bf16*)(ws + o);      o += (size_t)DMODEL * VOCAB * 2;

  hipMemsetAsync(ctl, 0, CTL_INTS * sizeof(int), stream);
  embed_gate<<<TOKENS, 256, 0, stream>>>(x, embed, Wg, bg, h_bf, top2i, top2w, ctl);
  scatter_k<<<1, 256, 0, stream>>>(top2i, ctl, tok2row, rowtok);
  transpose_cvt<<<dim3(HID/32, DMODEL/32, NEXP), 256, 0, stream>>>(W1, W1t, DMODEL, HID);
  transpose_cvt<<<dim3(DMODEL/32, HID/32, NEXP), 256, 0, stream>>>(W2, W2t, HID, DMODEL);
  transpose_cvt<<<dim3(VOCAB/32, DMODEL/32, 1), 256, 0, stream>>>(Wh, Wht, DMODEL, VOCAB);
  gemm128<0><<<dim3(MAXTILES, HID/128), 256, 0, stream>>>(h_bf, W1t, b1, nullptr, a_act, ctl, rowtok);
  gemm128<1><<<dim3(MAXTILES, DMODEL/128), 256, 0, stream>>>(a_act, W2t, b2, yrow, nullptr, ctl, nullptr);
  combine_ln<<<TOKENS, 256, 0, stream>>>(yrow, tok2row, top2w, gamma, beta, lnb);

  // head GEMM: 256x128 tiles, 2000 blocks, 2 blocks/CU
  gemm_head<<<dim3(2000), 512, 0, stream>>>(lnb, Wht, bh, out);
}